// Round 3
// baseline (504.886 us; speedup 1.0000x reference)
//
#include <hip/hip_runtime.h>
#include <hip/hip_bf16.h>
#include <stdint.h>

typedef __attribute__((ext_vector_type(8))) __bf16 bf16x8;
typedef __attribute__((ext_vector_type(4))) float f32x4;
typedef __attribute__((ext_vector_type(16))) float f32x16;

#define MFMA16(a, b, c) __builtin_amdgcn_mfma_f32_16x16x32_bf16((a), (b), (c), 0, 0, 0)
#define MFMA32(a, b, c) __builtin_amdgcn_mfma_f32_32x32x16_bf16((a), (b), (c), 0, 0, 0)

static __device__ __forceinline__ void gload_lds16(const void* g, void* l) {
  __builtin_amdgcn_global_load_lds(
      reinterpret_cast<const __attribute__((address_space(1))) uint32_t*>(
          reinterpret_cast<uintptr_t>(g)),
      reinterpret_cast<__attribute__((address_space(3))) uint32_t*>(
          reinterpret_cast<uintptr_t>(l)),
      16, 0, 0);
}

static __device__ __forceinline__ unsigned pack_bf16(float lo, float hi) {
  unsigned short lb = __builtin_bit_cast(unsigned short, (__bf16)lo);
  unsigned short hb = __builtin_bit_cast(unsigned short, (__bf16)hi);
  return ((unsigned)hb << 16) | (unsigned)lb;
}

// ---------------- fp32 -> bf16 copy convert (vectorized) ----------------
__global__ void cvt_f32_bf16(const float* __restrict__ in, __bf16* __restrict__ out, int n) {
  int i = (blockIdx.x * blockDim.x + threadIdx.x) * 8;
  if (i >= n) return;
  float4 a = *(const float4*)(in + i);
  float4 b = *(const float4*)(in + i + 4);
  bf16x8 o;
  o[0] = (__bf16)a.x; o[1] = (__bf16)a.y; o[2] = (__bf16)a.z; o[3] = (__bf16)a.w;
  o[4] = (__bf16)b.x; o[5] = (__bf16)b.y; o[6] = (__bf16)b.z; o[7] = (__bf16)b.w;
  *(bf16x8*)(out + i) = o;
}

// ---------- transpose + convert: in[R][C] f32 -> out[C][R] bf16 ----------
__global__ void transpose_cvt(const float* __restrict__ in, __bf16* __restrict__ out,
                              int R, int C) {
  __shared__ float tile[32][33];
  int c0 = blockIdx.x * 32, r0 = blockIdx.y * 32;
  int tx = threadIdx.x, ty = threadIdx.y;  // 32 x 8
#pragma unroll
  for (int i = 0; i < 4; i++)
    tile[ty + i * 8][tx] = in[(size_t)(r0 + ty + i * 8) * C + c0 + tx];
  __syncthreads();
#pragma unroll
  for (int i = 0; i < 4; i++)
    out[(size_t)(c0 + ty + i * 8) * R + r0 + tx] = (__bf16)tile[tx][ty + i * 8];
}

// ---------- V [BH][2048][64] -> Vt [BH][64][2048] (bf16) ----------
__global__ void transpose_v(const __bf16* __restrict__ V, __bf16* __restrict__ Vt) {
  __shared__ __bf16 tile[64][72];
  int bh = blockIdx.y, s0 = blockIdx.x * 64;
  int t = threadIdx.x;          // 256
  int r = t >> 2, cq = (t & 3) * 16;
  const __bf16* src = V + ((size_t)bh * 2048 + s0 + r) * 64 + cq;
  bf16x8 v0 = *(const bf16x8*)src;
  bf16x8 v1 = *(const bf16x8*)(src + 8);
#pragma unroll
  for (int j = 0; j < 8; j++) { tile[r][cq + j] = v0[j]; tile[r][cq + 8 + j] = v1[j]; }
  __syncthreads();
  int d = t >> 2, sq = (t & 3) * 16;
  bf16x8 o0, o1;
#pragma unroll
  for (int j = 0; j < 8; j++) { o0[j] = tile[sq + j][d]; o1[j] = tile[sq + 8 + j][d]; }
  __bf16* dst = Vt + ((size_t)bh * 64 + d) * 2048 + s0 + sq;
  *(bf16x8*)dst = o0;
  *(bf16x8*)(dst + 8) = o1;
}

// ---------------- GEMM: C[M,N] = A[M,1024] @ Bt[N,1024]^T ----------------
template <int EPI>
__global__ __launch_bounds__(256) void gemm_bt(
    const __bf16* __restrict__ A, const __bf16* __restrict__ Bt,
    const float* __restrict__ bias, float* __restrict__ Cf,
    __bf16* __restrict__ Qb, __bf16* __restrict__ Kb, __bf16* __restrict__ Vb, int N) {
  __shared__ __bf16 lA[128 * 32];
  __shared__ __bf16 lB[128 * 32];
  const int tM = blockIdx.x, tN = blockIdx.y;
  const int tid = threadIdx.x;
  const int w = tid >> 6, lane = tid & 63;
  const int wr = w >> 1, wc = w & 1;
  const int lr = lane & 15, lg = lane >> 4;

  const __bf16* As0 = A + (size_t)(tM * 128 + w * 16 + (lane >> 2)) * 1024 + (lane & 3) * 8;
  const __bf16* Bs0 = Bt + (size_t)(tN * 128 + w * 16 + (lane >> 2)) * 1024 + (lane & 3) * 8;
  __bf16* lA0 = &lA[w * 512];
  __bf16* lA1 = &lA[w * 512 + 2048];
  __bf16* lB0 = &lB[w * 512];
  __bf16* lB1 = &lB[w * 512 + 2048];

  f32x4 acc[4][4];
#pragma unroll
  for (int m = 0; m < 4; m++)
#pragma unroll
    for (int n = 0; n < 4; n++) acc[m][n] = f32x4{0.f, 0.f, 0.f, 0.f};

  for (int k0 = 0; k0 < 1024; k0 += 32) {
    gload_lds16(As0 + k0, lA0);
    gload_lds16(As0 + 64 * 1024 + k0, lA1);
    gload_lds16(Bs0 + k0, lB0);
    gload_lds16(Bs0 + 64 * 1024 + k0, lB1);
    __syncthreads();
    bf16x8 af[4], bfr[4];
#pragma unroll
    for (int m = 0; m < 4; m++)
      af[m] = *(const bf16x8*)&lA[(wr * 64 + m * 16 + lr) * 32 + lg * 8];
#pragma unroll
    for (int n = 0; n < 4; n++)
      bfr[n] = *(const bf16x8*)&lB[(wc * 64 + n * 16 + lr) * 32 + lg * 8];
#pragma unroll
    for (int m = 0; m < 4; m++)
#pragma unroll
      for (int n = 0; n < 4; n++) acc[m][n] = MFMA16(af[m], bfr[n], acc[m][n]);
    __syncthreads();
  }

#pragma unroll
  for (int m = 0; m < 4; m++) {
#pragma unroll
    for (int n = 0; n < 4; n++) {
      int row0 = tM * 128 + wr * 64 + m * 16 + lg * 4;
      int col = tN * 128 + wc * 64 + n * 16 + lr;
      float bv = bias[col];
      if (EPI == 0) {
        int which = col >> 10, rem = col & 1023;
        int hh = rem >> 6, dd = rem & 63;
        __bf16* dst = (which == 0) ? Qb : ((which == 1) ? Kb : Vb);
        float sc = (which == 0) ? 0.125f : 1.0f;  // fold 1/sqrt(64) into Q
#pragma unroll
        for (int r = 0; r < 4; r++) {
          int row = row0 + r;
          int b = row >> 11, s = row & 2047;
          dst[((size_t)(b * 16 + hh) * 2048 + s) * 64 + dd] = (__bf16)((acc[m][n][r] + bv) * sc);
        }
      } else {
#pragma unroll
        for (int r = 0; r < 4; r++)
          Cf[(size_t)(row0 + r) * N + col] = acc[m][n][r] + bv;
      }
    }
  }
}

// ---------------- flash causal attention: swapped QK^T, 32x32x16, in-register P ----
// grid: (16 q-tiles of 128 [reversed], 64 bh), block 256 (4 waves x 32 q-rows).
// Q,K: [BH][2048][64] bf16 (Q pre-scaled by 0.125); Vt: [BH][64][2048]; Y: [B,S,1024]
__global__ __launch_bounds__(256) void attn_fwd(
    const __bf16* __restrict__ Q, const __bf16* __restrict__ K,
    const __bf16* __restrict__ Vt, __bf16* __restrict__ Y) {
  const int qt = (int)gridDim.x - 1 - (int)blockIdx.x;  // big tiles first
  const int bh = blockIdx.y;
  const int w = threadIdx.x >> 6, lane = threadIdx.x & 63;
  const int l31 = lane & 31, hi = lane >> 5;
  const int b = bh >> 4, h = bh & 15;
  const int qbase = qt * 128 + w * 32;
  const int qg = qbase + l31;  // this lane's q-row (S/P orientation)
  const __bf16* Qp = Q + (size_t)bh * 131072;
  const __bf16* Kp = K + (size_t)bh * 131072;
  const __bf16* Vp = Vt + (size_t)bh * 131072;

  __shared__ __bf16 Kl[2][4096];  // [64 kv][64 d], XOR-swizzled 16B slots
  __shared__ __bf16 Vl[2][4096];  // [64 d][64 kv], XOR-swizzled 16B slots

  // Q B-frags: lane holds Q[qg][d = c*16 + hi*8 + j]
  bf16x8 qf[4];
#pragma unroll
  for (int c = 0; c < 4; c++)
    qf[c] = *(const bf16x8*)&Qp[(size_t)qg * 64 + c * 16 + hi * 8];

  f32x16 o0, o1;  // O acc: col d = nt*32 + l31, row q = (r&3)+8*(r>>2)+4*hi
#pragma unroll
  for (int i = 0; i < 16; i++) { o0[i] = 0.f; o1[i] = 0.f; }
  float m_run = -1e30f, l_run = 0.f;

  const int nt = 2 * qt + 2;

  auto stage = [&](int buf, int kv0_) {
#pragma unroll
    for (int is = 0; is < 2; is++) {
      int rr = w * 16 + is * 8 + (lane >> 3);
      int sc = ((lane & 7) ^ (rr & 7)) * 8;  // inverse-swizzled global source
      gload_lds16(Kp + (size_t)(kv0_ + rr) * 64 + sc, &Kl[buf][(w * 16 + is * 8) * 64]);
      gload_lds16(Vp + (size_t)rr * 2048 + kv0_ + sc, &Vl[buf][(w * 16 + is * 8) * 64]);
    }
  };

  stage(0, 0);
  __syncthreads();
  int cur = 0;

  for (int t = 0; t < nt; ++t) {
    const int kv0 = t * 64;
    if (t + 1 < nt) stage(cur ^ 1, kv0 + 64);  // prefetch next tile

    if (kv0 <= qbase + 31) {
      // ---- QK^T swapped: S^T = K @ Q^T; lane owns q=l31, 16 kv per subtile ----
      f32x16 s0, s1;
#pragma unroll
      for (int i = 0; i < 16; i++) { s0[i] = 0.f; s1[i] = 0.f; }
      __builtin_amdgcn_s_setprio(1);
#pragma unroll
      for (int c = 0; c < 4; c++) {
        int x = (c * 32 + hi * 16);
        int kva = l31, kvb = 32 + l31;
        bf16x8 kfa = *(const bf16x8*)&Kl[cur][kva * 64 + ((x ^ ((kva & 7) << 4)) >> 1)];
        bf16x8 kfb = *(const bf16x8*)&Kl[cur][kvb * 64 + ((x ^ ((kvb & 7) << 4)) >> 1)];
        s0 = MFMA32(kfa, qf[c], s0);
        s1 = MFMA32(kfb, qf[c], s1);
      }
      __builtin_amdgcn_s_setprio(0);

      // ---- in-register online softmax: lane = q-row; kv_local = (r&3)+8*(r>>2)+4*hi
      const bool diag = (kv0 + 63 > qbase);
      float smax = -1e30f;
#pragma unroll
      for (int r = 0; r < 16; r++) {
        if (diag) {
          int kvl = kv0 + (r & 3) + 8 * (r >> 2) + 4 * hi;
          if (kvl > qg) s0[r] = -1e30f;
          if (kvl + 32 > qg) s1[r] = -1e30f;
        }
        smax = fmaxf(smax, fmaxf(s0[r], s1[r]));
      }
      smax = fmaxf(smax, __shfl_xor(smax, 32));  // partner half holds other 32 kv
      bool need = smax > m_run + 8.f;            // defer-max THR=8
      if (__any(need)) {
        float mnew = fmaxf(m_run, smax);
        float alpha = __expf(m_run - mnew);
        m_run = mnew;
        l_run *= alpha;
#pragma unroll
        for (int r = 0; r < 16; r++) {
          float av = __shfl(alpha, (r & 3) + 8 * (r >> 2) + 4 * hi);
          o0[r] *= av;
          o1[r] *= av;
        }
      }
#pragma unroll
      for (int r = 0; r < 16; r++) {
        float e0 = __expf(s0[r] - m_run);
        float e1 = __expf(s1[r] - m_run);
        s0[r] = e0; s1[r] = e1;
        l_run += e0 + e1;  // own-kv partial; partner combined at epilogue
      }

      // ---- P -> bf16 A-frags in-register (pack pairs + lane^32 exchange) ----
      bf16x8 pa[4];
#pragma unroll
      for (int n = 0; n < 2; n++) {
#pragma unroll
        for (int g = 0; g < 2; g++) {
          int base = g * 8;
          unsigned a0, a1, b0, b1;
          if (n == 0) {
            a0 = pack_bf16(s0[base + 0], s0[base + 1]);
            a1 = pack_bf16(s0[base + 2], s0[base + 3]);
            b0 = pack_bf16(s0[base + 4], s0[base + 5]);
            b1 = pack_bf16(s0[base + 6], s0[base + 7]);
          } else {
            a0 = pack_bf16(s1[base + 0], s1[base + 1]);
            a1 = pack_bf16(s1[base + 2], s1[base + 3]);
            b0 = pack_bf16(s1[base + 4], s1[base + 5]);
            b1 = pack_bf16(s1[base + 6], s1[base + 7]);
          }
          unsigned oa0 = __shfl_xor(a0, 32), ob0 = __shfl_xor(b0, 32);
          unsigned oa1 = __shfl_xor(a1, 32), ob1 = __shfl_xor(b1, 32);
          union { unsigned u[4]; bf16x8 v; } pu;
          pu.u[0] = hi ? ob0 : a0;   // kv pair (hi*8+0, +1)
          pu.u[1] = hi ? ob1 : a1;   // kv pair (hi*8+2, +3)
          pu.u[2] = hi ? b0 : oa0;   // kv pair (hi*8+4, +5)
          pu.u[3] = hi ? b1 : oa1;   // kv pair (hi*8+6, +7)
          pa[n * 2 + g] = pu.v;
        }
      }

      // ---- PV: O += P @ V, V B-frags from swizzled Vt tile ----
      __builtin_amdgcn_s_setprio(1);
#pragma unroll
      for (int c = 0; c < 4; c++) {
        int x = (c * 32 + hi * 16);
        int da = l31, db = 32 + l31;
        bf16x8 vfa = *(const bf16x8*)&Vl[cur][da * 64 + ((x ^ ((da & 7) << 4)) >> 1)];
        bf16x8 vfb = *(const bf16x8*)&Vl[cur][db * 64 + ((x ^ ((db & 7) << 4)) >> 1)];
        o0 = MFMA32(pa[c], vfa, o0);
        o1 = MFMA32(pa[c], vfb, o1);
      }
      __builtin_amdgcn_s_setprio(0);
    }

    __syncthreads();  // drains prefetch + guards buffer reuse
    cur ^= 1;
  }

  // ---- epilogue: combine partner l, normalize, store ----
  float ltot = l_run + __shfl_xor(l_run, 32);
  float linv = 1.f / ltot;
#pragma unroll
  for (int r = 0; r < 16; r++) {
    int qsel = (r & 3) + 8 * (r >> 2) + 4 * hi;
    float iv = __shfl(linv, qsel);
    size_t row = (size_t)(b * 2048 + qbase + qsel);
    Y[row * 1024 + h * 64 + l31] = (__bf16)(o0[r] * iv);
    Y[row * 1024 + h * 64 + 32 + l31] = (__bf16)(o1[r] * iv);
  }
}

extern "C" void kernel_launch(void* const* d_in, const int* in_sizes, int n_in,
                              void* d_out, int out_size, void* d_ws, size_t ws_size,
                              hipStream_t stream) {
  const float* x = (const float*)d_in[0];
  const float* wqkv = (const float*)d_in[1];
  const float* bqkv = (const float*)d_in[2];
  const float* wo = (const float*)d_in[3];
  const float* bo = (const float*)d_in[4];
  float* out = (float*)d_out;

  __bf16* ws = (__bf16*)d_ws;
  __bf16* xb = ws;                      // 8,388,608 elems (reused as Y later)
  __bf16* wqkvT = xb + 8388608;         // 3,145,728
  __bf16* woT = wqkvT + 3145728;        // 1,048,576
  __bf16* Qb = woT + 1048576;           // 8,388,608
  __bf16* Kb = Qb + 8388608;            // 8,388,608
  __bf16* Vb = Kb + 8388608;            // 8,388,608
  __bf16* Vtb = Vb + 8388608;           // 8,388,608
  __bf16* Yb = xb;                      // alias: xb dead after gemm1

  cvt_f32_bf16<<<4096, 256, 0, stream>>>(x, xb, 8388608);
  dim3 tb(32, 8);
  transpose_cvt<<<dim3(96, 32), tb, 0, stream>>>(wqkv, wqkvT, 1024, 3072);
  transpose_cvt<<<dim3(32, 32), tb, 0, stream>>>(wo, woT, 1024, 1024);
  gemm_bt<0><<<dim3(64, 24), 256, 0, stream>>>(xb, wqkvT, bqkv, nullptr, Qb, Kb, Vb, 3072);
  transpose_v<<<dim3(32, 64), 256, 0, stream>>>(Vb, Vtb);
  attn_fwd<<<dim3(16, 64), 256, 0, stream>>>(Qb, Kb, Vtb, Yb);
  gemm_bt<1><<<dim3(64, 8), 256, 0, stream>>>(Yb, woT, bo, out, nullptr, nullptr, nullptr, 1024);
}

// Round 4
// 219.111 us; speedup vs baseline: 2.3042x; 2.3042x over previous
//
#include <hip/hip_runtime.h>
#include <hip/hip_bf16.h>
#include <stdint.h>

typedef __attribute__((ext_vector_type(8))) __bf16 bf16x8;
typedef __attribute__((ext_vector_type(4))) float f32x4;

#define MFMA16(a, b, c) __builtin_amdgcn_mfma_f32_16x16x32_bf16((a), (b), (c), 0, 0, 0)

static __device__ __forceinline__ void gload_lds16(const void* g, void* l) {
  __builtin_amdgcn_global_load_lds(
      reinterpret_cast<const __attribute__((address_space(1))) uint32_t*>(
          reinterpret_cast<uintptr_t>(g)),
      reinterpret_cast<__attribute__((address_space(3))) uint32_t*>(
          reinterpret_cast<uintptr_t>(l)),
      16, 0, 0);
}

// ---------------- fp32 -> bf16 copy convert (vectorized) ----------------
__global__ void cvt_f32_bf16(const float* __restrict__ in, __bf16* __restrict__ out, int n) {
  int i = (blockIdx.x * blockDim.x + threadIdx.x) * 8;
  if (i >= n) return;
  float4 a = *(const float4*)(in + i);
  float4 b = *(const float4*)(in + i + 4);
  bf16x8 o;
  o[0] = (__bf16)a.x; o[1] = (__bf16)a.y; o[2] = (__bf16)a.z; o[3] = (__bf16)a.w;
  o[4] = (__bf16)b.x; o[5] = (__bf16)b.y; o[6] = (__bf16)b.z; o[7] = (__bf16)b.w;
  *(bf16x8*)(out + i) = o;
}

// ---------- transpose + convert: in[R][C] f32 -> out[C][R] bf16 ----------
__global__ void transpose_cvt(const float* __restrict__ in, __bf16* __restrict__ out,
                              int R, int C) {
  __shared__ float tile[32][33];
  int c0 = blockIdx.x * 32, r0 = blockIdx.y * 32;
  int tx = threadIdx.x, ty = threadIdx.y;  // 32 x 8
#pragma unroll
  for (int i = 0; i < 4; i++)
    tile[ty + i * 8][tx] = in[(size_t)(r0 + ty + i * 8) * C + c0 + tx];
  __syncthreads();
#pragma unroll
  for (int i = 0; i < 4; i++)
    out[(size_t)(c0 + ty + i * 8) * R + r0 + tx] = (__bf16)tile[tx][ty + i * 8];
}

// ---------- V [BH][2048][64] -> Vt [BH][64][2048] (bf16) ----------
__global__ void transpose_v(const __bf16* __restrict__ V, __bf16* __restrict__ Vt) {
  __shared__ __bf16 tile[64][72];
  int bh = blockIdx.y, s0 = blockIdx.x * 64;
  int t = threadIdx.x;          // 256
  int r = t >> 2, cq = (t & 3) * 16;
  const __bf16* src = V + ((size_t)bh * 2048 + s0 + r) * 64 + cq;
  bf16x8 v0 = *(const bf16x8*)src;
  bf16x8 v1 = *(const bf16x8*)(src + 8);
#pragma unroll
  for (int j = 0; j < 8; j++) { tile[r][cq + j] = v0[j]; tile[r][cq + 8 + j] = v1[j]; }
  __syncthreads();
  int d = t >> 2, sq = (t & 3) * 16;
  bf16x8 o0, o1;
#pragma unroll
  for (int j = 0; j < 8; j++) { o0[j] = tile[sq + j][d]; o1[j] = tile[sq + 8 + j][d]; }
  __bf16* dst = Vt + ((size_t)bh * 64 + d) * 2048 + s0 + sq;
  *(bf16x8*)dst = o0;
  *(bf16x8*)(dst + 8) = o1;
}

// ---------------- GEMM: C[M,N] = A[M,1024] @ Bt[N,1024]^T ----------------
template <int EPI>
__global__ __launch_bounds__(256) void gemm_bt(
    const __bf16* __restrict__ A, const __bf16* __restrict__ Bt,
    const float* __restrict__ bias, float* __restrict__ Cf,
    __bf16* __restrict__ Qb, __bf16* __restrict__ Kb, __bf16* __restrict__ Vb, int N) {
  __shared__ __bf16 lA[128 * 32];
  __shared__ __bf16 lB[128 * 32];
  const int tM = blockIdx.x, tN = blockIdx.y;
  const int tid = threadIdx.x;
  const int w = tid >> 6, lane = tid & 63;
  const int wr = w >> 1, wc = w & 1;
  const int lr = lane & 15, lg = lane >> 4;

  const __bf16* As0 = A + (size_t)(tM * 128 + w * 16 + (lane >> 2)) * 1024 + (lane & 3) * 8;
  const __bf16* Bs0 = Bt + (size_t)(tN * 128 + w * 16 + (lane >> 2)) * 1024 + (lane & 3) * 8;
  __bf16* lA0 = &lA[w * 512];
  __bf16* lA1 = &lA[w * 512 + 2048];
  __bf16* lB0 = &lB[w * 512];
  __bf16* lB1 = &lB[w * 512 + 2048];

  f32x4 acc[4][4];
#pragma unroll
  for (int m = 0; m < 4; m++)
#pragma unroll
    for (int n = 0; n < 4; n++) acc[m][n] = f32x4{0.f, 0.f, 0.f, 0.f};

  for (int k0 = 0; k0 < 1024; k0 += 32) {
    gload_lds16(As0 + k0, lA0);
    gload_lds16(As0 + 64 * 1024 + k0, lA1);
    gload_lds16(Bs0 + k0, lB0);
    gload_lds16(Bs0 + 64 * 1024 + k0, lB1);
    __syncthreads();
    bf16x8 af[4], bfr[4];
#pragma unroll
    for (int m = 0; m < 4; m++)
      af[m] = *(const bf16x8*)&lA[(wr * 64 + m * 16 + lr) * 32 + lg * 8];
#pragma unroll
    for (int n = 0; n < 4; n++)
      bfr[n] = *(const bf16x8*)&lB[(wc * 64 + n * 16 + lr) * 32 + lg * 8];
#pragma unroll
    for (int m = 0; m < 4; m++)
#pragma unroll
      for (int n = 0; n < 4; n++) acc[m][n] = MFMA16(af[m], bfr[n], acc[m][n]);
    __syncthreads();
  }

#pragma unroll
  for (int m = 0; m < 4; m++) {
#pragma unroll
    for (int n = 0; n < 4; n++) {
      int row0 = tM * 128 + wr * 64 + m * 16 + lg * 4;
      int col = tN * 128 + wc * 64 + n * 16 + lr;
      float bv = bias[col];
      if (EPI == 0) {
        int which = col >> 10, rem = col & 1023;
        int hh = rem >> 6, dd = rem & 63;
        __bf16* dst = (which == 0) ? Qb : ((which == 1) ? Kb : Vb);
        float sc = (which == 0) ? 0.125f : 1.0f;  // fold 1/sqrt(64) into Q
#pragma unroll
        for (int r = 0; r < 4; r++) {
          int row = row0 + r;
          int b = row >> 11, s = row & 2047;
          dst[((size_t)(b * 16 + hh) * 2048 + s) * 64 + dd] = (__bf16)((acc[m][n][r] + bv) * sc);
        }
      } else {
#pragma unroll
        for (int r = 0; r < 4; r++)
          Cf[(size_t)(row0 + r) * N + col] = acc[m][n][r] + bv;
      }
    }
  }
}

// ---------------- flash causal attention (paired q-tiles, LDS-staged, dbuf) ----------
// grid: (8 pairs, 64 bh), block 256 (4 waves x 32 q-rows). Block handles q-tiles
// {pair, 15-pair} -> uniform 34 kv-tiles/block (load balance).
// Q,K: [BH][2048][64] bf16 (Q pre-scaled by 0.125); Vt: [BH][64][2048]; Y: [B,S,1024]
__global__ __launch_bounds__(256) void attn_fwd(
    const __bf16* __restrict__ Q, const __bf16* __restrict__ K,
    const __bf16* __restrict__ Vt, __bf16* __restrict__ Y) {
  const int pair = blockIdx.x;
  const int bh = blockIdx.y;
  const int w = threadIdx.x >> 6, lane = threadIdx.x & 63;
  const int lr = lane & 15, lg = lane >> 4;
  const int b = bh >> 4, h = bh & 15;
  const __bf16* Qp = Q + (size_t)bh * 131072;
  const __bf16* Kp = K + (size_t)bh * 131072;
  const __bf16* Vp = Vt + (size_t)bh * 131072;

  // K tile [64 kv][64 d], V tile [64 d][64 kv]; XOR-swizzled byte ^= (row&7)<<4
  __shared__ __bf16 Kl[2][4096];
  __shared__ __bf16 Vl[2][4096];
  __shared__ __bf16 Pl[4][32 * 72];
  __bf16* Pw = Pl[w];

  // stage kv block kv0_ into buffer buf (inverse-swizzled source, linear LDS dest)
  auto stage = [&](int buf, int kv0_) {
#pragma unroll
    for (int is = 0; is < 2; is++) {
      int rr = w * 16 + is * 8 + (lane >> 3);
      int sc = ((lane & 7) ^ (rr & 7)) * 8;
      gload_lds16(Kp + (size_t)(kv0_ + rr) * 64 + sc, &Kl[buf][(w * 16 + is * 8) * 64]);
      gload_lds16(Vp + (size_t)rr * 2048 + kv0_ + sc, &Vl[buf][(w * 16 + is * 8) * 64]);
    }
  };

  for (int sel = 0; sel < 2; ++sel) {
    const int qt = sel ? (15 - pair) : pair;
    const int qbase = qt * 128 + w * 32;

    // Q fragments: rows qbase + m*16 + lr, k = c*32 + lg*8
    bf16x8 aq[2][2];
#pragma unroll
    for (int m = 0; m < 2; m++)
#pragma unroll
      for (int c = 0; c < 2; c++)
        aq[m][c] = *(const bf16x8*)&Qp[(size_t)(qbase + m * 16 + lr) * 64 + c * 32 + lg * 8];

    f32x4 acc_o[2][4];
#pragma unroll
    for (int m = 0; m < 2; m++)
#pragma unroll
      for (int dn = 0; dn < 4; dn++) acc_o[m][dn] = f32x4{0.f, 0.f, 0.f, 0.f};
    float m_run[2][4], l_run[2][4];
#pragma unroll
    for (int m = 0; m < 2; m++)
#pragma unroll
      for (int r = 0; r < 4; r++) { m_run[m][r] = -1e30f; l_run[m][r] = 0.f; }

    const int nt = 2 * qt + 2;

    stage(0, 0);
    __syncthreads();
    int cur = 0;

    for (int t = 0; t < nt; ++t) {
      const int kv0 = t * 64;
      if (t + 1 < nt) stage(cur ^ 1, kv0 + 64);  // prefetch next tile (issue early)

      if (kv0 <= qbase + 31) {
        // ---- QK^T from LDS (swizzled reads) ----
        f32x4 s4[2][4];
#pragma unroll
        for (int m = 0; m < 2; m++)
#pragma unroll
          for (int n = 0; n < 4; n++) s4[m][n] = f32x4{0.f, 0.f, 0.f, 0.f};
        __builtin_amdgcn_s_setprio(1);
#pragma unroll
        for (int c = 0; c < 2; c++) {
#pragma unroll
          for (int n = 0; n < 4; n++) {
            int kr = n * 16 + lr;
            int off = kr * 64 + (((c * 64 + lg * 16) ^ ((kr & 7) << 4)) >> 1);
            bf16x8 bk = *(const bf16x8*)&Kl[cur][off];
#pragma unroll
            for (int m = 0; m < 2; m++) s4[m][n] = MFMA16(aq[m][c], bk, s4[m][n]);
          }
        }
        __builtin_amdgcn_s_setprio(0);

        // ---- online softmax (defer-max THR=8, deferred l-reduce) ----
        const bool fullvis = (kv0 + 63 <= qbase);
        float vmax_[2][4];
        bool need = false;
#pragma unroll
        for (int m = 0; m < 2; m++) {
#pragma unroll
          for (int r = 0; r < 4; r++) {
            const int qrow = qbase + m * 16 + lg * 4 + r;
            float vmax = -1e30f;
#pragma unroll
            for (int n = 0; n < 4; n++) {
              float sv = s4[m][n][r];
              if (!fullvis && (kv0 + n * 16 + lr > qrow)) sv = -1e30f;
              s4[m][n][r] = sv;
              vmax = fmaxf(vmax, sv);
            }
            vmax = fmaxf(vmax, __shfl_xor(vmax, 1));
            vmax = fmaxf(vmax, __shfl_xor(vmax, 2));
            vmax = fmaxf(vmax, __shfl_xor(vmax, 4));
            vmax = fmaxf(vmax, __shfl_xor(vmax, 8));
            vmax_[m][r] = vmax;
            need = need || (vmax > m_run[m][r] + 8.f);
          }
        }
        if (__any(need)) {
#pragma unroll
          for (int m = 0; m < 2; m++)
#pragma unroll
            for (int r = 0; r < 4; r++) {
              float mnew = fmaxf(m_run[m][r], vmax_[m][r]);
              float alpha = __expf(m_run[m][r] - mnew);
              m_run[m][r] = mnew;
              l_run[m][r] *= alpha;
#pragma unroll
              for (int dn = 0; dn < 4; dn++) acc_o[m][dn][r] *= alpha;
            }
        }
#pragma unroll
        for (int m = 0; m < 2; m++)
#pragma unroll
          for (int r = 0; r < 4; r++) {
            float rs = 0.f;
#pragma unroll
            for (int n = 0; n < 4; n++) {
              float e = __expf(s4[m][n][r] - m_run[m][r]);
              s4[m][n][r] = e;
              rs += e;
            }
            l_run[m][r] += rs;  // per-lane partial; reduced at epilogue
          }

        // ---- P (C-layout) -> LDS -> A-layout fragments ----
#pragma unroll
        for (int m = 0; m < 2; m++)
#pragma unroll
          for (int r = 0; r < 4; r++)
#pragma unroll
            for (int n = 0; n < 4; n++)
              Pw[(m * 16 + lg * 4 + r) * 72 + n * 16 + lr] = (__bf16)s4[m][n][r];
        bf16x8 ap[2][2];
#pragma unroll
        for (int m = 0; m < 2; m++)
#pragma unroll
          for (int cc = 0; cc < 2; cc++)
            ap[m][cc] = *(const bf16x8*)&Pw[(m * 16 + lr) * 72 + cc * 32 + lg * 8];

        // ---- PV from LDS V (swizzled reads) ----
        __builtin_amdgcn_s_setprio(1);
#pragma unroll
        for (int dn = 0; dn < 4; dn++) {
          int d = dn * 16 + lr;
#pragma unroll
          for (int cc = 0; cc < 2; cc++) {
            int off = d * 64 + (((cc * 64 + lg * 16) ^ ((d & 7) << 4)) >> 1);
            bf16x8 bv = *(const bf16x8*)&Vl[cur][off];
#pragma unroll
            for (int m = 0; m < 2; m++) acc_o[m][dn] = MFMA16(ap[m][cc], bv, acc_o[m][dn]);
          }
        }
        __builtin_amdgcn_s_setprio(0);
      }

      __syncthreads();  // drains stage (vmcnt) + guards buffer reuse
      cur ^= 1;
    }

    // epilogue: reduce l over the 16 lr lanes, normalize, store
#pragma unroll
    for (int m = 0; m < 2; m++) {
#pragma unroll
      for (int r = 0; r < 4; r++) {
        float lsum = l_run[m][r];
        lsum += __shfl_xor(lsum, 1);
        lsum += __shfl_xor(lsum, 2);
        lsum += __shfl_xor(lsum, 4);
        lsum += __shfl_xor(lsum, 8);
        float inv = 1.f / lsum;
        int row = b * 2048 + qbase + m * 16 + lg * 4 + r;
#pragma unroll
        for (int dn = 0; dn < 4; dn++)
          Y[(size_t)row * 1024 + h * 64 + dn * 16 + lr] = (__bf16)(acc_o[m][dn][r] * inv);
      }
    }
  }
}

extern "C" void kernel_launch(void* const* d_in, const int* in_sizes, int n_in,
                              void* d_out, int out_size, void* d_ws, size_t ws_size,
                              hipStream_t stream) {
  const float* x = (const float*)d_in[0];
  const float* wqkv = (const float*)d_in[1];
  const float* bqkv = (const float*)d_in[2];
  const float* wo = (const float*)d_in[3];
  const float* bo = (const float*)d_in[4];
  float* out = (float*)d_out;

  __bf16* ws = (__bf16*)d_ws;
  __bf16* xb = ws;                      // 8,388,608 elems (reused as Y later)
  __bf16* wqkvT = xb + 8388608;         // 3,145,728
  __bf16* woT = wqkvT + 3145728;        // 1,048,576
  __bf16* Qb = woT + 1048576;           // 8,388,608
  __bf16* Kb = Qb + 8388608;            // 8,388,608
  __bf16* Vb = Kb + 8388608;            // 8,388,608
  __bf16* Vtb = Vb + 8388608;           // 8,388,608
  __bf16* Yb = xb;                      // alias: xb dead after gemm1

  cvt_f32_bf16<<<4096, 256, 0, stream>>>(x, xb, 8388608);
  dim3 tb(32, 8);
  transpose_cvt<<<dim3(96, 32), tb, 0, stream>>>(wqkv, wqkvT, 1024, 3072);
  transpose_cvt<<<dim3(32, 32), tb, 0, stream>>>(wo, woT, 1024, 1024);
  gemm_bt<0><<<dim3(64, 24), 256, 0, stream>>>(xb, wqkvT, bqkv, nullptr, Qb, Kb, Vb, 3072);
  transpose_v<<<dim3(32, 64), 256, 0, stream>>>(Vb, Vtb);
  attn_fwd<<<dim3(8, 64), 256, 0, stream>>>(Qb, Kb, Vtb, Yb);
  gemm_bt<1><<<dim3(64, 8), 256, 0, stream>>>(Yb, woT, bo, out, nullptr, nullptr, nullptr, 1024);
}

// Round 5
// 192.024 us; speedup vs baseline: 2.6293x; 1.1411x over previous
//
#include <hip/hip_runtime.h>
#include <hip/hip_bf16.h>
#include <stdint.h>

typedef __attribute__((ext_vector_type(8))) __bf16 bf16x8;
typedef __attribute__((ext_vector_type(4))) __bf16 bf16x4;
typedef __attribute__((ext_vector_type(4))) float f32x4;

#define MFMA16(a, b, c) __builtin_amdgcn_mfma_f32_16x16x32_bf16((a), (b), (c), 0, 0, 0)

static __device__ __forceinline__ void gload_lds16(const void* g, void* l) {
  __builtin_amdgcn_global_load_lds(
      reinterpret_cast<const __attribute__((address_space(1))) uint32_t*>(
          reinterpret_cast<uintptr_t>(g)),
      reinterpret_cast<__attribute__((address_space(3))) uint32_t*>(
          reinterpret_cast<uintptr_t>(l)),
      16, 0, 0);
}

// ---------------- fp32 -> bf16 copy convert (vectorized) ----------------
__global__ void cvt_f32_bf16(const float* __restrict__ in, __bf16* __restrict__ out, int n) {
  int i = (blockIdx.x * blockDim.x + threadIdx.x) * 8;
  if (i >= n) return;
  float4 a = *(const float4*)(in + i);
  float4 b = *(const float4*)(in + i + 4);
  bf16x8 o;
  o[0] = (__bf16)a.x; o[1] = (__bf16)a.y; o[2] = (__bf16)a.z; o[3] = (__bf16)a.w;
  o[4] = (__bf16)b.x; o[5] = (__bf16)b.y; o[6] = (__bf16)b.z; o[7] = (__bf16)b.w;
  *(bf16x8*)(out + i) = o;
}

// ---------- transpose + convert: in[R][C] f32 -> out[C][R] bf16 ----------
__global__ void transpose_cvt(const float* __restrict__ in, __bf16* __restrict__ out,
                              int R, int C) {
  __shared__ float tile[32][33];
  int c0 = blockIdx.x * 32, r0 = blockIdx.y * 32;
  int tx = threadIdx.x, ty = threadIdx.y;  // 32 x 8
#pragma unroll
  for (int i = 0; i < 4; i++)
    tile[ty + i * 8][tx] = in[(size_t)(r0 + ty + i * 8) * C + c0 + tx];
  __syncthreads();
#pragma unroll
  for (int i = 0; i < 4; i++)
    out[(size_t)(c0 + ty + i * 8) * R + r0 + tx] = (__bf16)tile[tx][ty + i * 8];
}

// ---------- V [BH][2048][64] -> Vt [BH][64][2048] (bf16) ----------
__global__ void transpose_v(const __bf16* __restrict__ V, __bf16* __restrict__ Vt) {
  __shared__ __bf16 tile[64][72];
  int bh = blockIdx.y, s0 = blockIdx.x * 64;
  int t = threadIdx.x;          // 256
  int r = t >> 2, cq = (t & 3) * 16;
  const __bf16* src = V + ((size_t)bh * 2048 + s0 + r) * 64 + cq;
  bf16x8 v0 = *(const bf16x8*)src;
  bf16x8 v1 = *(const bf16x8*)(src + 8);
#pragma unroll
  for (int j = 0; j < 8; j++) { tile[r][cq + j] = v0[j]; tile[r][cq + 8 + j] = v1[j]; }
  __syncthreads();
  int d = t >> 2, sq = (t & 3) * 16;
  bf16x8 o0, o1;
#pragma unroll
  for (int j = 0; j < 8; j++) { o0[j] = tile[sq + j][d]; o1[j] = tile[sq + 8 + j][d]; }
  __bf16* dst = Vt + ((size_t)bh * 64 + d) * 2048 + s0 + sq;
  *(bf16x8*)dst = o0;
  *(bf16x8*)(dst + 8) = o1;
}

// ---------------- GEMM: C[M,N] = A[M,1024] @ Bt[N,1024]^T ----------------
template <int EPI>
__global__ __launch_bounds__(256) void gemm_bt(
    const __bf16* __restrict__ A, const __bf16* __restrict__ Bt,
    const float* __restrict__ bias, float* __restrict__ Cf,
    __bf16* __restrict__ Qb, __bf16* __restrict__ Kb, __bf16* __restrict__ Vb, int N) {
  __shared__ __bf16 lA[128 * 32];
  __shared__ __bf16 lB[128 * 32];
  const int tM = blockIdx.x, tN = blockIdx.y;
  const int tid = threadIdx.x;
  const int w = tid >> 6, lane = tid & 63;
  const int wr = w >> 1, wc = w & 1;
  const int lr = lane & 15, lg = lane >> 4;

  const __bf16* As0 = A + (size_t)(tM * 128 + w * 16 + (lane >> 2)) * 1024 + (lane & 3) * 8;
  const __bf16* Bs0 = Bt + (size_t)(tN * 128 + w * 16 + (lane >> 2)) * 1024 + (lane & 3) * 8;
  __bf16* lA0 = &lA[w * 512];
  __bf16* lA1 = &lA[w * 512 + 2048];
  __bf16* lB0 = &lB[w * 512];
  __bf16* lB1 = &lB[w * 512 + 2048];

  f32x4 acc[4][4];
#pragma unroll
  for (int m = 0; m < 4; m++)
#pragma unroll
    for (int n = 0; n < 4; n++) acc[m][n] = f32x4{0.f, 0.f, 0.f, 0.f};

  for (int k0 = 0; k0 < 1024; k0 += 32) {
    gload_lds16(As0 + k0, lA0);
    gload_lds16(As0 + 64 * 1024 + k0, lA1);
    gload_lds16(Bs0 + k0, lB0);
    gload_lds16(Bs0 + 64 * 1024 + k0, lB1);
    __syncthreads();
    bf16x8 af[4], bfr[4];
#pragma unroll
    for (int m = 0; m < 4; m++)
      af[m] = *(const bf16x8*)&lA[(wr * 64 + m * 16 + lr) * 32 + lg * 8];
#pragma unroll
    for (int n = 0; n < 4; n++)
      bfr[n] = *(const bf16x8*)&lB[(wc * 64 + n * 16 + lr) * 32 + lg * 8];
#pragma unroll
    for (int m = 0; m < 4; m++)
#pragma unroll
      for (int n = 0; n < 4; n++) acc[m][n] = MFMA16(af[m], bfr[n], acc[m][n]);
    __syncthreads();
  }

#pragma unroll
  for (int m = 0; m < 4; m++) {
#pragma unroll
    for (int n = 0; n < 4; n++) {
      int row0 = tM * 128 + wr * 64 + m * 16 + lg * 4;
      int col = tN * 128 + wc * 64 + n * 16 + lr;
      float bv = bias[col];
      if (EPI == 0) {
        int which = col >> 10, rem = col & 1023;
        int hh = rem >> 6, dd = rem & 63;
        __bf16* dst = (which == 0) ? Qb : ((which == 1) ? Kb : Vb);
        // fold softmax scale AND log2(e) into Q so attn exp becomes raw v_exp_f32
        float sc = (which == 0) ? 0.18033688f : 1.0f;  // 0.125 * log2(e)
#pragma unroll
        for (int r = 0; r < 4; r++) {
          int row = row0 + r;
          int b = row >> 11, s = row & 2047;
          dst[((size_t)(b * 16 + hh) * 2048 + s) * 64 + dd] = (__bf16)((acc[m][n][r] + bv) * sc);
        }
      } else {
#pragma unroll
        for (int r = 0; r < 4; r++)
          Cf[(size_t)(row0 + r) * N + col] = acc[m][n][r] + bv;
      }
    }
  }
}

// ---------------- flash causal attention (paired q-tiles, swapped QK^T) ----------
// grid: (8 pairs, 64 bh), block 256 (4 waves x 32 q-rows). Block handles q-tiles
// {pair, 15-pair} -> uniform 34 kv-tiles/block.
// S^T = mfma(K_frag, Q_frag): lane owns q = qbase + m*16 + lr, kv = kv0+n*16+lg*4+r.
// All scores are in log2-domain (Q pre-scaled by 0.125*log2e).
__global__ __launch_bounds__(256) void attn_fwd(
    const __bf16* __restrict__ Q, const __bf16* __restrict__ K,
    const __bf16* __restrict__ Vt, __bf16* __restrict__ Y) {
  const int pair = blockIdx.x;
  const int bh = blockIdx.y;
  const int w = threadIdx.x >> 6, lane = threadIdx.x & 63;
  const int lr = lane & 15, lg = lane >> 4;
  const int b = bh >> 4, h = bh & 15;
  const __bf16* Qp = Q + (size_t)bh * 131072;
  const __bf16* Kp = K + (size_t)bh * 131072;
  const __bf16* Vp = Vt + (size_t)bh * 131072;

  // K tile [64 kv][64 d], V tile [64 d][64 kv]; XOR-swizzled byte ^= (row&7)<<4
  __shared__ __bf16 Kl[2][4096];
  __shared__ __bf16 Vl[2][4096];
  __shared__ __bf16 Pl[4][32 * 72];
  __bf16* Pw = Pl[w];

  auto stage = [&](int buf, int kv0_) {
#pragma unroll
    for (int is = 0; is < 2; is++) {
      int rr = w * 16 + is * 8 + (lane >> 3);
      int sc = ((lane & 7) ^ (rr & 7)) * 8;
      gload_lds16(Kp + (size_t)(kv0_ + rr) * 64 + sc, &Kl[buf][(w * 16 + is * 8) * 64]);
      gload_lds16(Vp + (size_t)rr * 2048 + kv0_ + sc, &Vl[buf][(w * 16 + is * 8) * 64]);
    }
  };

  for (int sel = 0; sel < 2; ++sel) {
    const int qt = sel ? (15 - pair) : pair;
    const int qbase = qt * 128 + w * 32;

    // Q fragments (B-operand): lane holds Q[qbase+m*16+lr][c*32+lg*8+j]
    bf16x8 aq[2][2];
#pragma unroll
    for (int m = 0; m < 2; m++)
#pragma unroll
      for (int c = 0; c < 2; c++)
        aq[m][c] = *(const bf16x8*)&Qp[(size_t)(qbase + m * 16 + lr) * 64 + c * 32 + lg * 8];

    f32x4 acc_o[2][4];
#pragma unroll
    for (int m = 0; m < 2; m++)
#pragma unroll
      for (int dn = 0; dn < 4; dn++) acc_o[m][dn] = f32x4{0.f, 0.f, 0.f, 0.f};
    float m_run[2], l_run[2];
#pragma unroll
    for (int m = 0; m < 2; m++) { m_run[m] = -1e30f; l_run[m] = 0.f; }

    const int nt = 2 * qt + 2;

    stage(0, 0);
    __syncthreads();
    int cur = 0;

    for (int t = 0; t < nt; ++t) {
      const int kv0 = t * 64;
      if (t + 1 < nt) stage(cur ^ 1, kv0 + 64);  // prefetch next tile (issue early)

      if (kv0 <= qbase + 31) {
        // ---- QK^T swapped: S^T[kv][q] = K @ Q^T (swizzled K reads) ----
        f32x4 s4[2][4];
#pragma unroll
        for (int m = 0; m < 2; m++)
#pragma unroll
          for (int n = 0; n < 4; n++) s4[m][n] = f32x4{0.f, 0.f, 0.f, 0.f};
        __builtin_amdgcn_s_setprio(1);
#pragma unroll
        for (int c = 0; c < 2; c++) {
#pragma unroll
          for (int n = 0; n < 4; n++) {
            int kr = n * 16 + lr;
            int off = kr * 64 + (((c * 64 + lg * 16) ^ ((kr & 7) << 4)) >> 1);
            bf16x8 bk = *(const bf16x8*)&Kl[cur][off];
#pragma unroll
            for (int m = 0; m < 2; m++) s4[m][n] = MFMA16(bk, aq[m][c], s4[m][n]);
          }
        }
        __builtin_amdgcn_s_setprio(0);

        // ---- online softmax: lane owns rows q = qbase+m*16+lr ----
        const bool diag = (kv0 + 63 > qbase);
        float vmax2[2];
#pragma unroll
        for (int m = 0; m < 2; m++) {
          const int qrow = qbase + m * 16 + lr;
          float vm = -1e30f;
#pragma unroll
          for (int n = 0; n < 4; n++)
#pragma unroll
            for (int r = 0; r < 4; r++) {
              float sv = s4[m][n][r];
              if (diag && (kv0 + n * 16 + lg * 4 + r > qrow)) { sv = -1e30f; s4[m][n][r] = sv; }
              vm = fmaxf(vm, sv);
            }
          vm = fmaxf(vm, __shfl_xor(vm, 16));
          vm = fmaxf(vm, __shfl_xor(vm, 32));
          vmax2[m] = vm;
        }
        bool need = (vmax2[0] > m_run[0] + 11.5f) || (vmax2[1] > m_run[1] + 11.5f);
        if (__any(need)) {  // defer-max (THR = 8*log2e)
          float alpha[2];
#pragma unroll
          for (int m = 0; m < 2; m++) {
            float mnew = fmaxf(m_run[m], vmax2[m]);
            alpha[m] = __builtin_amdgcn_exp2f(m_run[m] - mnew);
            m_run[m] = mnew;
            l_run[m] *= alpha[m];
          }
#pragma unroll
          for (int m = 0; m < 2; m++)
#pragma unroll
            for (int r = 0; r < 4; r++) {
              float av = __shfl(alpha[m], (lane & 48) | (lg * 4 + r));
#pragma unroll
              for (int dn = 0; dn < 4; dn++) acc_o[m][dn][r] *= av;
            }
        }
        // exp (single v_exp each) + in-lane l partial + packed P write (b64)
#pragma unroll
        for (int m = 0; m < 2; m++) {
          float rs = 0.f;
#pragma unroll
          for (int n = 0; n < 4; n++) {
            bf16x4 pq;
#pragma unroll
            for (int r = 0; r < 4; r++) {
              float e = __builtin_amdgcn_exp2f(s4[m][n][r] - m_run[m]);
              rs += e;
              pq[r] = (__bf16)e;
            }
            *(bf16x4*)&Pw[(m * 16 + lr) * 72 + n * 16 + lg * 4] = pq;
          }
          l_run[m] += rs;
        }

        // ---- P A-frags from LDS ----
        bf16x8 ap[2][2];
#pragma unroll
        for (int m = 0; m < 2; m++)
#pragma unroll
          for (int cc = 0; cc < 2; cc++)
            ap[m][cc] = *(const bf16x8*)&Pw[(m * 16 + lr) * 72 + cc * 32 + lg * 8];

        // ---- PV from LDS V (swizzled reads) ----
        __builtin_amdgcn_s_setprio(1);
#pragma unroll
        for (int dn = 0; dn < 4; dn++) {
          int d = dn * 16 + lr;
#pragma unroll
          for (int cc = 0; cc < 2; cc++) {
            int off = d * 64 + (((cc * 64 + lg * 16) ^ ((d & 7) << 4)) >> 1);
            bf16x8 bv = *(const bf16x8*)&Vl[cur][off];
#pragma unroll
            for (int m = 0; m < 2; m++) acc_o[m][dn] = MFMA16(ap[m][cc], bv, acc_o[m][dn]);
          }
        }
        __builtin_amdgcn_s_setprio(0);
      }

      __syncthreads();  // drains stage (vmcnt) + guards buffer reuse
      cur ^= 1;
    }

    // epilogue: reduce l across lg lanes, route 1/l to O rows, store
#pragma unroll
    for (int m = 0; m < 2; m++) {
      float lsum = l_run[m];
      lsum += __shfl_xor(lsum, 16);
      lsum += __shfl_xor(lsum, 32);
      float linv = 1.f / lsum;
#pragma unroll
      for (int r = 0; r < 4; r++) {
        float iv = __shfl(linv, (lane & 48) | (lg * 4 + r));
        int row = b * 2048 + qbase + m * 16 + lg * 4 + r;
#pragma unroll
        for (int dn = 0; dn < 4; dn++)
          Y[(size_t)row * 1024 + h * 64 + dn * 16 + lr] = (__bf16)(acc_o[m][dn][r] * iv);
      }
    }
  }
}

extern "C" void kernel_launch(void* const* d_in, const int* in_sizes, int n_in,
                              void* d_out, int out_size, void* d_ws, size_t ws_size,
                              hipStream_t stream) {
  const float* x = (const float*)d_in[0];
  const float* wqkv = (const float*)d_in[1];
  const float* bqkv = (const float*)d_in[2];
  const float* wo = (const float*)d_in[3];
  const float* bo = (const float*)d_in[4];
  float* out = (float*)d_out;

  __bf16* ws = (__bf16*)d_ws;
  __bf16* xb = ws;                      // 8,388,608 elems (reused as Y later)
  __bf16* wqkvT = xb + 8388608;         // 3,145,728
  __bf16* woT = wqkvT + 3145728;        // 1,048,576
  __bf16* Qb = woT + 1048576;           // 8,388,608
  __bf16* Kb = Qb + 8388608;            // 8,388,608
  __bf16* Vb = Kb + 8388608;            // 8,388,608
  __bf16* Vtb = Vb + 8388608;           // 8,388,608
  __bf16* Yb = xb;                      // alias: xb dead after gemm1

  cvt_f32_bf16<<<4096, 256, 0, stream>>>(x, xb, 8388608);
  dim3 tb(32, 8);
  transpose_cvt<<<dim3(96, 32), tb, 0, stream>>>(wqkv, wqkvT, 1024, 3072);
  transpose_cvt<<<dim3(32, 32), tb, 0, stream>>>(wo, woT, 1024, 1024);
  gemm_bt<0><<<dim3(64, 24), 256, 0, stream>>>(xb, wqkvT, bqkv, nullptr, Qb, Kb, Vb, 3072);
  transpose_v<<<dim3(32, 64), 256, 0, stream>>>(Vb, Vtb);
  attn_fwd<<<dim3(8, 64), 256, 0, stream>>>(Qb, Kb, Vtb, Yb);
  gemm_bt<1><<<dim3(64, 8), 256, 0, stream>>>(Yb, woT, bo, out, nullptr, nullptr, nullptr, 1024);
}

// Round 6
// 185.628 us; speedup vs baseline: 2.7199x; 1.0345x over previous
//
#include <hip/hip_runtime.h>
#include <hip/hip_bf16.h>
#include <stdint.h>

typedef __attribute__((ext_vector_type(8))) __bf16 bf16x8;
typedef __attribute__((ext_vector_type(4))) __bf16 bf16x4;
typedef __attribute__((ext_vector_type(4))) float f32x4;

#define MFMA16(a, b, c) __builtin_amdgcn_mfma_f32_16x16x32_bf16((a), (b), (c), 0, 0, 0)

static __device__ __forceinline__ void gload_lds16(const void* g, void* l) {
  __builtin_amdgcn_global_load_lds(
      reinterpret_cast<const __attribute__((address_space(1))) uint32_t*>(
          reinterpret_cast<uintptr_t>(g)),
      reinterpret_cast<__attribute__((address_space(3))) uint32_t*>(
          reinterpret_cast<uintptr_t>(l)),
      16, 0, 0);
}

// ---------------- fp32 -> bf16 copy convert (vectorized) ----------------
__global__ void cvt_f32_bf16(const float* __restrict__ in, __bf16* __restrict__ out, int n) {
  int i = (blockIdx.x * blockDim.x + threadIdx.x) * 8;
  if (i >= n) return;
  float4 a = *(const float4*)(in + i);
  float4 b = *(const float4*)(in + i + 4);
  bf16x8 o;
  o[0] = (__bf16)a.x; o[1] = (__bf16)a.y; o[2] = (__bf16)a.z; o[3] = (__bf16)a.w;
  o[4] = (__bf16)b.x; o[5] = (__bf16)b.y; o[6] = (__bf16)b.z; o[7] = (__bf16)b.w;
  *(bf16x8*)(out + i) = o;
}

// ---------- transpose + convert: in[R][C] f32 -> out[C][R] bf16 ----------
__global__ void transpose_cvt(const float* __restrict__ in, __bf16* __restrict__ out,
                              int R, int C) {
  __shared__ float tile[32][33];
  int c0 = blockIdx.x * 32, r0 = blockIdx.y * 32;
  int tx = threadIdx.x, ty = threadIdx.y;  // 32 x 8
#pragma unroll
  for (int i = 0; i < 4; i++)
    tile[ty + i * 8][tx] = in[(size_t)(r0 + ty + i * 8) * C + c0 + tx];
  __syncthreads();
#pragma unroll
  for (int i = 0; i < 4; i++)
    out[(size_t)(c0 + ty + i * 8) * R + r0 + tx] = (__bf16)tile[tx][ty + i * 8];
}

// ---------- V [BH][2048][64] -> Vt [BH][64][2048] (bf16) ----------
__global__ void transpose_v(const __bf16* __restrict__ V, __bf16* __restrict__ Vt) {
  __shared__ __bf16 tile[64][72];
  int bh = blockIdx.y, s0 = blockIdx.x * 64;
  int t = threadIdx.x;          // 256
  int r = t >> 2, cq = (t & 3) * 16;
  const __bf16* src = V + ((size_t)bh * 2048 + s0 + r) * 64 + cq;
  bf16x8 v0 = *(const bf16x8*)src;
  bf16x8 v1 = *(const bf16x8*)(src + 8);
#pragma unroll
  for (int j = 0; j < 8; j++) { tile[r][cq + j] = v0[j]; tile[r][cq + 8 + j] = v1[j]; }
  __syncthreads();
  int d = t >> 2, sq = (t & 3) * 16;
  bf16x8 o0, o1;
#pragma unroll
  for (int j = 0; j < 8; j++) { o0[j] = tile[sq + j][d]; o1[j] = tile[sq + 8 + j][d]; }
  __bf16* dst = Vt + ((size_t)bh * 64 + d) * 2048 + s0 + sq;
  *(bf16x8*)dst = o0;
  *(bf16x8*)(dst + 8) = o1;
}

// ------- GEMM (pipelined): C[M,N] = A[M,1024] @ Bt[N,1024]^T -------
// BM=128, BN=256, BK=32, 512 threads (8 waves 2Mx4N), 4-slot LDS rotation,
// 3-tile prefetch lead, counted vmcnt(6) per K-tile (T3+T4), raw s_barrier.
// LDS read swizzle: 16B-slot = lg ^ ((row>>1)&3) (inverse-swizzled source).
// EPI==0: scatter to Q/K/V [4,16,2048,64] bf16 (+bias, Q scaled)
// EPI==1: fp32 store to Cf [M,N] (+bias)
template <int EPI>
__global__ __launch_bounds__(512) void gemm_pipe(
    const __bf16* __restrict__ A, const __bf16* __restrict__ Bt,
    const float* __restrict__ bias, float* __restrict__ Cf,
    __bf16* __restrict__ Qb, __bf16* __restrict__ Kb, __bf16* __restrict__ Vb, int N) {
  __shared__ __bf16 lA[4][128 * 32];
  __shared__ __bf16 lB[4][256 * 32];
  const int tM = blockIdx.x, tN = blockIdx.y;
  const int tid = threadIdx.x;
  const int w = tid >> 6, lane = tid & 63;
  const int wr = w >> 2, wc = w & 3;
  const int lr = lane & 15, lg = lane >> 4;

  // staging source (pre-swizzled): LDS linear slot (tid&3) holds global slot g
  const int srow = tid >> 2;
  const int gcol = ((tid & 3) ^ ((tid >> 3) & 3)) * 8;
  const __bf16* Asrc = A + (size_t)(tM * 128 + srow) * 1024 + gcol;
  const __bf16* Bsrc0 = Bt + (size_t)(tN * 256 + srow) * 1024 + gcol;
  const __bf16* Bsrc1 = Bt + (size_t)(tN * 256 + 128 + srow) * 1024 + gcol;

  f32x4 acc[4][4];
#pragma unroll
  for (int m = 0; m < 4; m++)
#pragma unroll
    for (int n = 0; n < 4; n++) acc[m][n] = f32x4{0.f, 0.f, 0.f, 0.f};

  auto stage = [&](int slot, int t) {
    const int k0 = t * 32;
    gload_lds16(Asrc + k0, &lA[slot][tid * 8]);
    gload_lds16(Bsrc0 + k0, &lB[slot][tid * 8]);
    gload_lds16(Bsrc1 + k0, &lB[slot][4096 + tid * 8]);
  };

  // read-side swizzled 16B slot (rows within a frag share (lr>>1)&3 pattern)
  const int aslot = (lg ^ ((lr >> 1) & 3)) * 8;
  auto compute = [&](int slot) {
    bf16x8 a[4], b[4];
#pragma unroll
    for (int m = 0; m < 4; m++) {
      int row = wr * 64 + m * 16 + lr;
      a[m] = *(const bf16x8*)&lA[slot][row * 32 + aslot];
    }
#pragma unroll
    for (int n = 0; n < 4; n++) {
      int row = wc * 64 + n * 16 + lr;
      b[n] = *(const bf16x8*)&lB[slot][row * 32 + aslot];
    }
    __builtin_amdgcn_s_setprio(1);
#pragma unroll
    for (int m = 0; m < 4; m++)
#pragma unroll
      for (int n = 0; n < 4; n++) acc[m][n] = MFMA16(a[m], b[n], acc[m][n]);
    __builtin_amdgcn_s_setprio(0);
  };

  // prologue: 3 tiles in flight, wait tile0 (6 newer loads outstanding)
  stage(0, 0); stage(1, 1); stage(2, 2);
  asm volatile("s_waitcnt vmcnt(6)" ::: "memory");
  __builtin_amdgcn_s_barrier();

#pragma unroll 1
  for (int t = 0; t < 29; ++t) {
    stage((t + 3) & 3, t + 3);   // issue next-next-next tile (3 loads)
    compute(t & 3);
    // wait tile t+1 only: tiles t+2,t+3 stay in flight across the barrier
    asm volatile("s_waitcnt vmcnt(6)" ::: "memory");
    __builtin_amdgcn_s_barrier();
  }
  compute(29 & 3);
  asm volatile("s_waitcnt vmcnt(3)" ::: "memory");
  __builtin_amdgcn_s_barrier();
  compute(30 & 3);
  asm volatile("s_waitcnt vmcnt(0)" ::: "memory");
  __builtin_amdgcn_s_barrier();
  compute(31 & 3);

#pragma unroll
  for (int m = 0; m < 4; m++) {
#pragma unroll
    for (int n = 0; n < 4; n++) {
      int row0 = tM * 128 + wr * 64 + m * 16 + lg * 4;
      int col = tN * 256 + wc * 64 + n * 16 + lr;
      float bv = bias[col];
      if (EPI == 0) {
        int which = col >> 10, rem = col & 1023;
        int hh = rem >> 6, dd = rem & 63;
        __bf16* dst = (which == 0) ? Qb : ((which == 1) ? Kb : Vb);
        // fold softmax scale AND log2(e) into Q (attn works in log2 domain)
        float sc = (which == 0) ? 0.18033688f : 1.0f;  // 0.125 * log2(e)
#pragma unroll
        for (int r = 0; r < 4; r++) {
          int row = row0 + r;
          int b = row >> 11, s = row & 2047;
          dst[((size_t)(b * 16 + hh) * 2048 + s) * 64 + dd] = (__bf16)((acc[m][n][r] + bv) * sc);
        }
      } else {
#pragma unroll
        for (int r = 0; r < 4; r++)
          Cf[(size_t)(row0 + r) * N + col] = acc[m][n][r] + bv;
      }
    }
  }
}

// ---------------- flash causal attention (paired q-tiles, swapped QK^T) ----------
// grid: (8 pairs, 64 bh), block 256 (4 waves x 32 q-rows). Block handles q-tiles
// {pair, 15-pair} -> uniform 34 kv-tiles/block.
// S^T = mfma(K_frag, Q_frag): lane owns q = qbase + m*16 + lr, kv = kv0+n*16+lg*4+r.
// All scores are in log2-domain (Q pre-scaled by 0.125*log2e).
__global__ __launch_bounds__(256) void attn_fwd(
    const __bf16* __restrict__ Q, const __bf16* __restrict__ K,
    const __bf16* __restrict__ Vt, __bf16* __restrict__ Y) {
  const int pair = blockIdx.x;
  const int bh = blockIdx.y;
  const int w = threadIdx.x >> 6, lane = threadIdx.x & 63;
  const int lr = lane & 15, lg = lane >> 4;
  const int b = bh >> 4, h = bh & 15;
  const __bf16* Qp = Q + (size_t)bh * 131072;
  const __bf16* Kp = K + (size_t)bh * 131072;
  const __bf16* Vp = Vt + (size_t)bh * 131072;

  // K tile [64 kv][64 d], V tile [64 d][64 kv]; XOR-swizzled byte ^= (row&7)<<4
  __shared__ __bf16 Kl[2][4096];
  __shared__ __bf16 Vl[2][4096];
  __shared__ __bf16 Pl[4][32 * 72];
  __bf16* Pw = Pl[w];

  auto stage = [&](int buf, int kv0_) {
#pragma unroll
    for (int is = 0; is < 2; is++) {
      int rr = w * 16 + is * 8 + (lane >> 3);
      int sc = ((lane & 7) ^ (rr & 7)) * 8;
      gload_lds16(Kp + (size_t)(kv0_ + rr) * 64 + sc, &Kl[buf][(w * 16 + is * 8) * 64]);
      gload_lds16(Vp + (size_t)rr * 2048 + kv0_ + sc, &Vl[buf][(w * 16 + is * 8) * 64]);
    }
  };

  for (int sel = 0; sel < 2; ++sel) {
    const int qt = sel ? (15 - pair) : pair;
    const int qbase = qt * 128 + w * 32;

    // Q fragments (B-operand): lane holds Q[qbase+m*16+lr][c*32+lg*8+j]
    bf16x8 aq[2][2];
#pragma unroll
    for (int m = 0; m < 2; m++)
#pragma unroll
      for (int c = 0; c < 2; c++)
        aq[m][c] = *(const bf16x8*)&Qp[(size_t)(qbase + m * 16 + lr) * 64 + c * 32 + lg * 8];

    f32x4 acc_o[2][4];
#pragma unroll
    for (int m = 0; m < 2; m++)
#pragma unroll
      for (int dn = 0; dn < 4; dn++) acc_o[m][dn] = f32x4{0.f, 0.f, 0.f, 0.f};
    float m_run[2], l_run[2];
#pragma unroll
    for (int m = 0; m < 2; m++) { m_run[m] = -1e30f; l_run[m] = 0.f; }

    const int nt = 2 * qt + 2;

    stage(0, 0);
    __syncthreads();
    int cur = 0;

    for (int t = 0; t < nt; ++t) {
      const int kv0 = t * 64;
      if (t + 1 < nt) stage(cur ^ 1, kv0 + 64);  // prefetch next tile (issue early)

      if (kv0 <= qbase + 31) {
        // ---- QK^T swapped: S^T[kv][q] = K @ Q^T (swizzled K reads) ----
        f32x4 s4[2][4];
#pragma unroll
        for (int m = 0; m < 2; m++)
#pragma unroll
          for (int n = 0; n < 4; n++) s4[m][n] = f32x4{0.f, 0.f, 0.f, 0.f};
        __builtin_amdgcn_s_setprio(1);
#pragma unroll
        for (int c = 0; c < 2; c++) {
#pragma unroll
          for (int n = 0; n < 4; n++) {
            int kr = n * 16 + lr;
            int off = kr * 64 + (((c * 64 + lg * 16) ^ ((kr & 7) << 4)) >> 1);
            bf16x8 bk = *(const bf16x8*)&Kl[cur][off];
#pragma unroll
            for (int m = 0; m < 2; m++) s4[m][n] = MFMA16(bk, aq[m][c], s4[m][n]);
          }
        }
        __builtin_amdgcn_s_setprio(0);

        // ---- online softmax: lane owns rows q = qbase+m*16+lr ----
        const bool diag = (kv0 + 63 > qbase);
        float vmax2[2];
#pragma unroll
        for (int m = 0; m < 2; m++) {
          const int qrow = qbase + m * 16 + lr;
          float vm = -1e30f;
#pragma unroll
          for (int n = 0; n < 4; n++)
#pragma unroll
            for (int r = 0; r < 4; r++) {
              float sv = s4[m][n][r];
              if (diag && (kv0 + n * 16 + lg * 4 + r > qrow)) { sv = -1e30f; s4[m][n][r] = sv; }
              vm = fmaxf(vm, sv);
            }
          vm = fmaxf(vm, __shfl_xor(vm, 16));
          vm = fmaxf(vm, __shfl_xor(vm, 32));
          vmax2[m] = vm;
        }
        bool need = (vmax2[0] > m_run[0] + 11.5f) || (vmax2[1] > m_run[1] + 11.5f);
        if (__any(need)) {  // defer-max (THR = 8*log2e)
          float alpha[2];
#pragma unroll
          for (int m = 0; m < 2; m++) {
            float mnew = fmaxf(m_run[m], vmax2[m]);
            alpha[m] = __builtin_amdgcn_exp2f(m_run[m] - mnew);
            m_run[m] = mnew;
            l_run[m] *= alpha[m];
          }
#pragma unroll
          for (int m = 0; m < 2; m++)
#pragma unroll
            for (int r = 0; r < 4; r++) {
              float av = __shfl(alpha[m], (lane & 48) | (lg * 4 + r));
#pragma unroll
              for (int dn = 0; dn < 4; dn++) acc_o[m][dn][r] *= av;
            }
        }
        // exp (single v_exp each) + in-lane l partial + packed P write (b64)
#pragma unroll
        for (int m = 0; m < 2; m++) {
          float rs = 0.f;
#pragma unroll
          for (int n = 0; n < 4; n++) {
            bf16x4 pq;
#pragma unroll
            for (int r = 0; r < 4; r++) {
              float e = __builtin_amdgcn_exp2f(s4[m][n][r] - m_run[m]);
              rs += e;
              pq[r] = (__bf16)e;
            }
            *(bf16x4*)&Pw[(m * 16 + lr) * 72 + n * 16 + lg * 4] = pq;
          }
          l_run[m] += rs;
        }

        // ---- P A-frags from LDS ----
        bf16x8 ap[2][2];
#pragma unroll
        for (int m = 0; m < 2; m++)
#pragma unroll
          for (int cc = 0; cc < 2; cc++)
            ap[m][cc] = *(const bf16x8*)&Pw[(m * 16 + lr) * 72 + cc * 32 + lg * 8];

        // ---- PV from LDS V (swizzled reads) ----
        __builtin_amdgcn_s_setprio(1);
#pragma unroll
        for (int dn = 0; dn < 4; dn++) {
          int d = dn * 16 + lr;
#pragma unroll
          for (int cc = 0; cc < 2; cc++) {
            int off = d * 64 + (((cc * 64 + lg * 16) ^ ((d & 7) << 4)) >> 1);
            bf16x8 bv = *(const bf16x8*)&Vl[cur][off];
#pragma unroll
            for (int m = 0; m < 2; m++) acc_o[m][dn] = MFMA16(ap[m][cc], bv, acc_o[m][dn]);
          }
        }
        __builtin_amdgcn_s_setprio(0);
      }

      __syncthreads();  // drains stage (vmcnt) + guards buffer reuse
      cur ^= 1;
    }

    // epilogue: reduce l across lg lanes, route 1/l to O rows, store
#pragma unroll
    for (int m = 0; m < 2; m++) {
      float lsum = l_run[m];
      lsum += __shfl_xor(lsum, 16);
      lsum += __shfl_xor(lsum, 32);
      float linv = 1.f / lsum;
#pragma unroll
      for (int r = 0; r < 4; r++) {
        float iv = __shfl(linv, (lane & 48) | (lg * 4 + r));
        int row = b * 2048 + qbase + m * 16 + lg * 4 + r;
#pragma unroll
        for (int dn = 0; dn < 4; dn++)
          Y[(size_t)row * 1024 + h * 64 + dn * 16 + lr] = (__bf16)(acc_o[m][dn][r] * iv);
      }
    }
  }
}

extern "C" void kernel_launch(void* const* d_in, const int* in_sizes, int n_in,
                              void* d_out, int out_size, void* d_ws, size_t ws_size,
                              hipStream_t stream) {
  const float* x = (const float*)d_in[0];
  const float* wqkv = (const float*)d_in[1];
  const float* bqkv = (const float*)d_in[2];
  const float* wo = (const float*)d_in[3];
  const float* bo = (const float*)d_in[4];
  float* out = (float*)d_out;

  __bf16* ws = (__bf16*)d_ws;
  __bf16* xb = ws;                      // 8,388,608 elems (reused as Y later)
  __bf16* wqkvT = xb + 8388608;         // 3,145,728
  __bf16* woT = wqkvT + 3145728;        // 1,048,576
  __bf16* Qb = woT + 1048576;           // 8,388,608
  __bf16* Kb = Qb + 8388608;            // 8,388,608
  __bf16* Vb = Kb + 8388608;            // 8,388,608
  __bf16* Vtb = Vb + 8388608;           // 8,388,608
  __bf16* Yb = xb;                      // alias: xb dead after gemm1

  cvt_f32_bf16<<<4096, 256, 0, stream>>>(x, xb, 8388608);
  dim3 tb(32, 8);
  transpose_cvt<<<dim3(96, 32), tb, 0, stream>>>(wqkv, wqkvT, 1024, 3072);
  transpose_cvt<<<dim3(32, 32), tb, 0, stream>>>(wo, woT, 1024, 1024);
  gemm_pipe<0><<<dim3(64, 12), 512, 0, stream>>>(xb, wqkvT, bqkv, nullptr, Qb, Kb, Vb, 3072);
  transpose_v<<<dim3(32, 64), 256, 0, stream>>>(Vb, Vtb);
  attn_fwd<<<dim3(8, 64), 256, 0, stream>>>(Qb, Kb, Vtb, Yb);
  gemm_pipe<1><<<dim3(64, 4), 512, 0, stream>>>(Yb, woT, bo, out, nullptr, nullptr, nullptr, 1024);
}

// Round 7
// 178.681 us; speedup vs baseline: 2.8256x; 1.0389x over previous
//
#include <hip/hip_runtime.h>
#include <hip/hip_bf16.h>
#include <stdint.h>

typedef __attribute__((ext_vector_type(8))) __bf16 bf16x8;
typedef __attribute__((ext_vector_type(4))) __bf16 bf16x4;
typedef __attribute__((ext_vector_type(4))) float f32x4;

#define MFMA16(a, b, c) __builtin_amdgcn_mfma_f32_16x16x32_bf16((a), (b), (c), 0, 0, 0)

static __device__ __forceinline__ void gload_lds16(const void* g, void* l) {
  __builtin_amdgcn_global_load_lds(
      reinterpret_cast<const __attribute__((address_space(1))) uint32_t*>(
          reinterpret_cast<uintptr_t>(g)),
      reinterpret_cast<__attribute__((address_space(3))) uint32_t*>(
          reinterpret_cast<uintptr_t>(l)),
      16, 0, 0);
}

// ---------------- fp32 -> bf16 copy convert (vectorized) ----------------
__global__ void cvt_f32_bf16(const float* __restrict__ in, __bf16* __restrict__ out, int n) {
  int i = (blockIdx.x * blockDim.x + threadIdx.x) * 8;
  if (i >= n) return;
  float4 a = *(const float4*)(in + i);
  float4 b = *(const float4*)(in + i + 4);
  bf16x8 o;
  o[0] = (__bf16)a.x; o[1] = (__bf16)a.y; o[2] = (__bf16)a.z; o[3] = (__bf16)a.w;
  o[4] = (__bf16)b.x; o[5] = (__bf16)b.y; o[6] = (__bf16)b.z; o[7] = (__bf16)b.w;
  *(bf16x8*)(out + i) = o;
}

// ---------- transpose + convert: in[R][C] f32 -> out[C][R] bf16 ----------
__global__ void transpose_cvt(const float* __restrict__ in, __bf16* __restrict__ out,
                              int R, int C) {
  __shared__ float tile[32][33];
  int c0 = blockIdx.x * 32, r0 = blockIdx.y * 32;
  int tx = threadIdx.x, ty = threadIdx.y;  // 32 x 8
#pragma unroll
  for (int i = 0; i < 4; i++)
    tile[ty + i * 8][tx] = in[(size_t)(r0 + ty + i * 8) * C + c0 + tx];
  __syncthreads();
#pragma unroll
  for (int i = 0; i < 4; i++)
    out[(size_t)(c0 + ty + i * 8) * R + r0 + tx] = (__bf16)tile[tx][ty + i * 8];
}

// ---------- V [BH][2048][64] -> Vt [BH][64][2048] (bf16) ----------
__global__ void transpose_v(const __bf16* __restrict__ V, __bf16* __restrict__ Vt) {
  __shared__ __bf16 tile[64][72];
  int bh = blockIdx.y, s0 = blockIdx.x * 64;
  int t = threadIdx.x;          // 256
  int r = t >> 2, cq = (t & 3) * 16;
  const __bf16* src = V + ((size_t)bh * 2048 + s0 + r) * 64 + cq;
  bf16x8 v0 = *(const bf16x8*)src;
  bf16x8 v1 = *(const bf16x8*)(src + 8);
#pragma unroll
  for (int j = 0; j < 8; j++) { tile[r][cq + j] = v0[j]; tile[r][cq + 8 + j] = v1[j]; }
  __syncthreads();
  int d = t >> 2, sq = (t & 3) * 16;
  bf16x8 o0, o1;
#pragma unroll
  for (int j = 0; j < 8; j++) { o0[j] = tile[sq + j][d]; o1[j] = tile[sq + 8 + j][d]; }
  __bf16* dst = Vt + ((size_t)bh * 64 + d) * 2048 + s0 + sq;
  *(bf16x8*)dst = o0;
  *(bf16x8*)(dst + 8) = o1;
}

// ------- GEMM (pipelined): C[M,N] = A[M,1024] @ Bt[N,1024]^T -------
// BM=128, BN=256, BK=32, 512 threads (8 waves 2Mx4N), 4-slot LDS rotation,
// 3-tile prefetch lead, counted vmcnt(6) per K-tile (T3+T4), raw s_barrier.
// XCD-aware bijective block swizzle (T1): requires nwg % 8 == 0.
template <int EPI>
__global__ __launch_bounds__(512) void gemm_pipe(
    const __bf16* __restrict__ A, const __bf16* __restrict__ Bt,
    const float* __restrict__ bias, float* __restrict__ Cf,
    __bf16* __restrict__ Qb, __bf16* __restrict__ Kb, __bf16* __restrict__ Vb, int N) {
  __shared__ __bf16 lA[4][128 * 32];
  __shared__ __bf16 lB[4][256 * 32];
  // XCD swizzle: contiguous chunk of original ids per XCD (nwg divisible by 8)
  const int nwg = (int)(gridDim.x * gridDim.y);
  const int bid0 = (int)(blockIdx.y * gridDim.x + blockIdx.x);
  const int bid = (bid0 & 7) * (nwg >> 3) + (bid0 >> 3);
  const int tM = bid & 63, tN = bid >> 6;  // gridDim.x == 64
  const int tid = threadIdx.x;
  const int w = tid >> 6, lane = tid & 63;
  const int wr = w >> 2, wc = w & 3;
  const int lr = lane & 15, lg = lane >> 4;

  // staging source (pre-swizzled): LDS linear slot (tid&3) holds global slot g
  const int srow = tid >> 2;
  const int gcol = ((tid & 3) ^ ((tid >> 3) & 3)) * 8;
  const __bf16* Asrc = A + (size_t)(tM * 128 + srow) * 1024 + gcol;
  const __bf16* Bsrc0 = Bt + (size_t)(tN * 256 + srow) * 1024 + gcol;
  const __bf16* Bsrc1 = Bt + (size_t)(tN * 256 + 128 + srow) * 1024 + gcol;

  f32x4 acc[4][4];
#pragma unroll
  for (int m = 0; m < 4; m++)
#pragma unroll
    for (int n = 0; n < 4; n++) acc[m][n] = f32x4{0.f, 0.f, 0.f, 0.f};

  auto stage = [&](int slot, int t) {
    const int k0 = t * 32;
    gload_lds16(Asrc + k0, &lA[slot][tid * 8]);
    gload_lds16(Bsrc0 + k0, &lB[slot][tid * 8]);
    gload_lds16(Bsrc1 + k0, &lB[slot][4096 + tid * 8]);
  };

  // read-side swizzled 16B slot (rows within a frag share (lr>>1)&3 pattern)
  const int aslot = (lg ^ ((lr >> 1) & 3)) * 8;
  auto compute = [&](int slot) {
    bf16x8 a[4], b[4];
#pragma unroll
    for (int m = 0; m < 4; m++) {
      int row = wr * 64 + m * 16 + lr;
      a[m] = *(const bf16x8*)&lA[slot][row * 32 + aslot];
    }
#pragma unroll
    for (int n = 0; n < 4; n++) {
      int row = wc * 64 + n * 16 + lr;
      b[n] = *(const bf16x8*)&lB[slot][row * 32 + aslot];
    }
    __builtin_amdgcn_s_setprio(1);
#pragma unroll
    for (int m = 0; m < 4; m++)
#pragma unroll
      for (int n = 0; n < 4; n++) acc[m][n] = MFMA16(a[m], b[n], acc[m][n]);
    __builtin_amdgcn_s_setprio(0);
  };

  // prologue: 3 tiles in flight, wait tile0 (6 newer loads outstanding)
  stage(0, 0); stage(1, 1); stage(2, 2);
  asm volatile("s_waitcnt vmcnt(6)" ::: "memory");
  __builtin_amdgcn_s_barrier();

#pragma unroll 1
  for (int t = 0; t < 29; ++t) {
    stage((t + 3) & 3, t + 3);   // issue next-next-next tile (3 loads)
    compute(t & 3);
    // wait tile t+1 only: tiles t+2,t+3 stay in flight across the barrier
    asm volatile("s_waitcnt vmcnt(6)" ::: "memory");
    __builtin_amdgcn_s_barrier();
  }
  compute(29 & 3);
  asm volatile("s_waitcnt vmcnt(3)" ::: "memory");
  __builtin_amdgcn_s_barrier();
  compute(30 & 3);
  asm volatile("s_waitcnt vmcnt(0)" ::: "memory");
  __builtin_amdgcn_s_barrier();
  compute(31 & 3);

#pragma unroll
  for (int m = 0; m < 4; m++) {
#pragma unroll
    for (int n = 0; n < 4; n++) {
      int row0 = tM * 128 + wr * 64 + m * 16 + lg * 4;
      int col = tN * 256 + wc * 64 + n * 16 + lr;
      float bv = bias[col];
      if (EPI == 0) {
        int which = col >> 10, rem = col & 1023;
        int hh = rem >> 6, dd = rem & 63;
        __bf16* dst = (which == 0) ? Qb : ((which == 1) ? Kb : Vb);
        // fold softmax scale AND log2(e) into Q (attn works in log2 domain)
        float sc = (which == 0) ? 0.18033688f : 1.0f;  // 0.125 * log2(e)
#pragma unroll
        for (int r = 0; r < 4; r++) {
          int row = row0 + r;
          int b = row >> 11, s = row & 2047;
          dst[((size_t)(b * 16 + hh) * 2048 + s) * 64 + dd] = (__bf16)((acc[m][n][r] + bv) * sc);
        }
      } else {
#pragma unroll
        for (int r = 0; r < 4; r++)
          Cf[(size_t)(row0 + r) * N + col] = acc[m][n][r] + bv;
      }
    }
  }
}

// ---------------- flash causal attention (paired q-tiles, swapped QK^T) ----------
// grid: (8 pairs, 64 bh), block 256 (4 waves x 32 q-rows). Block handles q-tiles
// {pair, 15-pair} -> uniform 34 kv-tiles/block.
// S^T = mfma(K_frag, Q_frag): lane owns q = qbase + m*16 + lr, kv = kv0+n*16+lg*4+r.
// All scores in log2-domain (Q pre-scaled by 0.125*log2e).
// l is accumulated on the MFMA pipe via an all-ones B operand (lands in O layout).
__global__ __launch_bounds__(256) void attn_fwd(
    const __bf16* __restrict__ Q, const __bf16* __restrict__ K,
    const __bf16* __restrict__ Vt, __bf16* __restrict__ Y) {
  const int pair = blockIdx.x;
  const int bh = blockIdx.y;
  const int w = threadIdx.x >> 6, lane = threadIdx.x & 63;
  const int lr = lane & 15, lg = lane >> 4;
  const int b = bh >> 4, h = bh & 15;
  const __bf16* Qp = Q + (size_t)bh * 131072;
  const __bf16* Kp = K + (size_t)bh * 131072;
  const __bf16* Vp = Vt + (size_t)bh * 131072;

  // K tile [64 kv][64 d], V tile [64 d][64 kv]; XOR-swizzled byte ^= (row&7)<<4
  __shared__ __bf16 Kl[2][4096];
  __shared__ __bf16 Vl[2][4096];
  __shared__ __bf16 Pl[4][32 * 72];
  __bf16* Pw = Pl[w];

  bf16x8 kones;
#pragma unroll
  for (int j = 0; j < 8; j++) kones[j] = (__bf16)1.0f;

  auto stage = [&](int buf, int kv0_) {
#pragma unroll
    for (int is = 0; is < 2; is++) {
      int rr = w * 16 + is * 8 + (lane >> 3);
      int sc = ((lane & 7) ^ (rr & 7)) * 8;
      gload_lds16(Kp + (size_t)(kv0_ + rr) * 64 + sc, &Kl[buf][(w * 16 + is * 8) * 64]);
      gload_lds16(Vp + (size_t)rr * 2048 + kv0_ + sc, &Vl[buf][(w * 16 + is * 8) * 64]);
    }
  };

  for (int sel = 0; sel < 2; ++sel) {
    const int qt = sel ? (15 - pair) : pair;
    const int qbase = qt * 128 + w * 32;

    // Q fragments (B-operand): lane holds Q[qbase+m*16+lr][c*32+lg*8+j]
    bf16x8 aq[2][2];
#pragma unroll
    for (int m = 0; m < 2; m++)
#pragma unroll
      for (int c = 0; c < 2; c++)
        aq[m][c] = *(const bf16x8*)&Qp[(size_t)(qbase + m * 16 + lr) * 64 + c * 32 + lg * 8];

    f32x4 acc_o[2][4];
    f32x4 acc_l[2];
#pragma unroll
    for (int m = 0; m < 2; m++) {
#pragma unroll
      for (int dn = 0; dn < 4; dn++) acc_o[m][dn] = f32x4{0.f, 0.f, 0.f, 0.f};
      acc_l[m] = f32x4{0.f, 0.f, 0.f, 0.f};
    }
    float m_run[2];
#pragma unroll
    for (int m = 0; m < 2; m++) m_run[m] = -1e30f;

    const int nt = 2 * qt + 2;

    stage(0, 0);
    __syncthreads();
    int cur = 0;

    for (int t = 0; t < nt; ++t) {
      const int kv0 = t * 64;
      if (t + 1 < nt) stage(cur ^ 1, kv0 + 64);  // prefetch next tile (issue early)

      if (kv0 <= qbase + 31) {
        // ---- QK^T swapped: S^T[kv][q] = K @ Q^T (swizzled K reads) ----
        f32x4 s4[2][4];
#pragma unroll
        for (int m = 0; m < 2; m++)
#pragma unroll
          for (int n = 0; n < 4; n++) s4[m][n] = f32x4{0.f, 0.f, 0.f, 0.f};
        __builtin_amdgcn_s_setprio(1);
#pragma unroll
        for (int c = 0; c < 2; c++) {
#pragma unroll
          for (int n = 0; n < 4; n++) {
            int kr = n * 16 + lr;
            int off = kr * 64 + (((c * 64 + lg * 16) ^ ((kr & 7) << 4)) >> 1);
            bf16x8 bk = *(const bf16x8*)&Kl[cur][off];
#pragma unroll
            for (int m = 0; m < 2; m++) s4[m][n] = MFMA16(bk, aq[m][c], s4[m][n]);
          }
        }
        __builtin_amdgcn_s_setprio(0);

        // ---- mask (diag tiles only) + max3-structured row max ----
        const bool diag = (kv0 + 63 > qbase);
        float vmax2[2];
#pragma unroll
        for (int m = 0; m < 2; m++) {
          const int qrow = qbase + m * 16 + lr;
          if (diag) {
#pragma unroll
            for (int n = 0; n < 4; n++)
#pragma unroll
              for (int r = 0; r < 4; r++)
                if (kv0 + n * 16 + lg * 4 + r > qrow) s4[m][n][r] = -1e30f;
          }
          float a0 = fmaxf(fmaxf(s4[m][0][0], s4[m][0][1]), s4[m][0][2]);
          float a1 = fmaxf(fmaxf(s4[m][0][3], s4[m][1][0]), s4[m][1][1]);
          float a2 = fmaxf(fmaxf(s4[m][1][2], s4[m][1][3]), s4[m][2][0]);
          float a3 = fmaxf(fmaxf(s4[m][2][1], s4[m][2][2]), s4[m][2][3]);
          float a4 = fmaxf(fmaxf(s4[m][3][0], s4[m][3][1]), s4[m][3][2]);
          float vm = fmaxf(fmaxf(fmaxf(a0, a1), a2), fmaxf(fmaxf(a3, a4), s4[m][3][3]));
          vm = fmaxf(vm, __shfl_xor(vm, 16));
          vm = fmaxf(vm, __shfl_xor(vm, 32));
          vmax2[m] = vm;
        }
        bool need = (vmax2[0] > m_run[0] + 11.5f) || (vmax2[1] > m_run[1] + 11.5f);
        if (__any(need)) {  // defer-max (THR = 8*log2e)
          float alpha[2];
#pragma unroll
          for (int m = 0; m < 2; m++) {
            float mnew = fmaxf(m_run[m], vmax2[m]);
            alpha[m] = __builtin_amdgcn_exp2f(m_run[m] - mnew);
            m_run[m] = mnew;
          }
#pragma unroll
          for (int m = 0; m < 2; m++)
#pragma unroll
            for (int r = 0; r < 4; r++) {
              float av = __shfl(alpha[m], (lane & 48) | (lg * 4 + r));
              acc_l[m][r] *= av;
#pragma unroll
              for (int dn = 0; dn < 4; dn++) acc_o[m][dn][r] *= av;
            }
        }
        // exp (single v_exp each) + packed P write (b64); l comes from MFMA below
#pragma unroll
        for (int m = 0; m < 2; m++) {
#pragma unroll
          for (int n = 0; n < 4; n++) {
            bf16x4 pq;
#pragma unroll
            for (int r = 0; r < 4; r++)
              pq[r] = (__bf16)__builtin_amdgcn_exp2f(s4[m][n][r] - m_run[m]);
            *(bf16x4*)&Pw[(m * 16 + lr) * 72 + n * 16 + lg * 4] = pq;
          }
        }

        // ---- P A-frags from LDS ----
        bf16x8 ap[2][2];
#pragma unroll
        for (int m = 0; m < 2; m++)
#pragma unroll
          for (int cc = 0; cc < 2; cc++)
            ap[m][cc] = *(const bf16x8*)&Pw[(m * 16 + lr) * 72 + cc * 32 + lg * 8];

        // ---- PV + l-row (ones trick) from LDS V (swizzled reads) ----
        __builtin_amdgcn_s_setprio(1);
#pragma unroll
        for (int m = 0; m < 2; m++)
#pragma unroll
          for (int cc = 0; cc < 2; cc++)
            acc_l[m] = MFMA16(ap[m][cc], kones, acc_l[m]);
#pragma unroll
        for (int dn = 0; dn < 4; dn++) {
          int d = dn * 16 + lr;
#pragma unroll
          for (int cc = 0; cc < 2; cc++) {
            int off = d * 64 + (((cc * 64 + lg * 16) ^ ((d & 7) << 4)) >> 1);
            bf16x8 bv = *(const bf16x8*)&Vl[cur][off];
#pragma unroll
            for (int m = 0; m < 2; m++) acc_o[m][dn] = MFMA16(ap[m][cc], bv, acc_o[m][dn]);
          }
        }
        __builtin_amdgcn_s_setprio(0);
      }

      __syncthreads();  // drains stage (vmcnt) + guards buffer reuse
      cur ^= 1;
    }

    // epilogue: acc_l already in O row layout -> no cross-lane reduce needed
#pragma unroll
    for (int m = 0; m < 2; m++) {
#pragma unroll
      for (int r = 0; r < 4; r++) {
        float iv = 1.f / acc_l[m][r];
        int row = b * 2048 + qbase + m * 16 + lg * 4 + r;
#pragma unroll
        for (int dn = 0; dn < 4; dn++)
          Y[(size_t)row * 1024 + h * 64 + dn * 16 + lr] = (__bf16)(acc_o[m][dn][r] * iv);
      }
    }
  }
}

extern "C" void kernel_launch(void* const* d_in, const int* in_sizes, int n_in,
                              void* d_out, int out_size, void* d_ws, size_t ws_size,
                              hipStream_t stream) {
  const float* x = (const float*)d_in[0];
  const float* wqkv = (const float*)d_in[1];
  const float* bqkv = (const float*)d_in[2];
  const float* wo = (const float*)d_in[3];
  const float* bo = (const float*)d_in[4];
  float* out = (float*)d_out;

  __bf16* ws = (__bf16*)d_ws;
  __bf16* xb = ws;                      // 8,388,608 elems (reused as Y later)
  __bf16* wqkvT = xb + 8388608;         // 3,145,728
  __bf16* woT = wqkvT + 3145728;        // 1,048,576
  __bf16* Qb = woT + 1048576;           // 8,388,608
  __bf16* Kb = Qb + 8388608;            // 8,388,608
  __bf16* Vb = Kb + 8388608;            // 8,388,608
  __bf16* Vtb = Vb + 8388608;           // 8,388,608
  __bf16* Yb = xb;                      // alias: xb dead after gemm1

  cvt_f32_bf16<<<4096, 256, 0, stream>>>(x, xb, 8388608);
  dim3 tb(32, 8);
  transpose_cvt<<<dim3(96, 32), tb, 0, stream>>>(wqkv, wqkvT, 1024, 3072);
  transpose_cvt<<<dim3(32, 32), tb, 0, stream>>>(wo, woT, 1024, 1024);
  gemm_pipe<0><<<dim3(64, 12), 512, 0, stream>>>(xb, wqkvT, bqkv, nullptr, Qb, Kb, Vb, 3072);
  transpose_v<<<dim3(32, 64), 256, 0, stream>>>(Vb, Vtb);
  attn_fwd<<<dim3(8, 64), 256, 0, stream>>>(Qb, Kb, Vtb, Yb);
  gemm_pipe<1><<<dim3(64, 4), 512, 0, stream>>>(Yb, woT, bo, out, nullptr, nullptr, nullptr, 1024);
}